// Round 5
// baseline (16012.550 us; speedup 1.0000x reference)
//
#include <hip/hip_runtime.h>
#include <hip/hip_bf16.h>

#define BB 2
#define SS 2048
#define NH 32
#define NKV 8
#define GQ (NH / NKV)
#define DD 128
#define QBLK 128
#define KVBLK 64
#define NQT (SS / QBLK)
#define NTHREADS 512

typedef __bf16 bf16x8 __attribute__((ext_vector_type(8)));
typedef short short8 __attribute__((ext_vector_type(8)));
typedef unsigned int u32x4 __attribute__((ext_vector_type(4)));

__device__ inline bf16x8 cvt_bf16x8(float4 a, float4 b) {
  bf16x8 r;
  r[0] = (__bf16)a.x; r[1] = (__bf16)a.y; r[2] = (__bf16)a.z; r[3] = (__bf16)a.w;
  r[4] = (__bf16)b.x; r[5] = (__bf16)b.y; r[6] = (__bf16)b.z; r[7] = (__bf16)b.w;
  return r;
}

__device__ inline float bf2f(short s) {
  unsigned u = ((unsigned)(unsigned short)s) << 16;
  return __builtin_bit_cast(float, u);
}

// SKELETON BISECT: identical wave/tile skeleton to R1/R3 (grid map, qt
// reversal, 16-row wave ownership, ntiles/skip, mask, online softmax,
// P->LDS->PV roundtrip, epilogue), but fp32 UNSWIZZLED LDS for K/V/P and
// scalar fp32 dots. Only Q is bf16. Tests the skeleton; strips the
// swizzle/bf16-slot layer.
__global__ __launch_bounds__(NTHREADS, 1)
void attn_skel(const float* __restrict__ qp, const float* __restrict__ kp,
               const float* __restrict__ vp, float* __restrict__ op)
{
  __shared__ float kbuf[KVBLK][DD];      // K tile fp32, unswizzled (32KB)
  __shared__ float vbuf[DD][KVBLK];      // V^T tile fp32, unswizzled (32KB)
  __shared__ float pbuf[8][16][KVBLK];   // per-wave P fp32, unswizzled (32KB)
  __shared__ u32x4 qbuf[8 * 16 * 16];    // per-wave Q bf16 (32KB), as R3

  const int tid  = threadIdx.x;
  const int wave = tid >> 6;
  const int lane = tid & 63;
  const int lhi  = lane >> 4;
  const int llo  = lane & 15;

  const int bid = blockIdx.x;
  const int bh  = bid % (BB * NH);
  const int qt  = NQT - 1 - bid / (BB * NH);
  const int b   = bh / NH;
  const int h   = bh % NH;
  const int kh  = h / GQ;

  const int q0 = qt * QBLK;
  const int qw = q0 + wave * 16;

  const float scale = 0.08838834764831845f;   // 1/sqrt(128)

  u32x4* qbuf_w = qbuf + wave * 256;
  {
    const float* qrow = qp + (((size_t)b * SS + (qw + llo)) * NH + h) * DD;
    #pragma unroll
    for (int kc = 0; kc < 4; ++kc) {
      const int d0 = kc * 32 + lhi * 8;
      float4 a = *(const float4*)(qrow + d0);
      float4 c = *(const float4*)(qrow + d0 + 4);
      a.x *= scale; a.y *= scale; a.z *= scale; a.w *= scale;
      c.x *= scale; c.y *= scale; c.z *= scale; c.w *= scale;
      qbuf_w[llo * 16 + kc * 4 + lhi] = __builtin_bit_cast(u32x4, cvt_bf16x8(a, c));
    }
  }

  float oaccf[8][4];
  #pragma unroll
  for (int f = 0; f < 8; ++f)
    #pragma unroll
    for (int j = 0; j < 4; ++j) oaccf[f][j] = 0.f;
  float m_i[4], l_i[4];
  #pragma unroll
  for (int j = 0; j < 4; ++j) { m_i[j] = -1e30f; l_i[j] = 0.f; }

  const int ntiles = q0 / KVBLK + 2;

  for (int t = 0; t < ntiles; ++t) {
    const int t0 = t * KVBLK;
    __syncthreads();

    // ---- stage K tile (fp32, unswizzled) ----
    #pragma unroll
    for (int it = 0; it < 2; ++it) {
      const int c   = tid + it * NTHREADS;   // 0..1023
      const int row = c >> 4, c16 = c & 15;
      const float* src = kp + (((size_t)b * SS + (t0 + row)) * NKV + kh) * DD + c16 * 8;
      #pragma unroll
      for (int e = 0; e < 8; ++e) kbuf[row][c16 * 8 + e] = src[e];
    }
    // ---- stage V^T tile (fp32, unswizzled) ----
    #pragma unroll
    for (int it = 0; it < 2; ++it) {
      const int c  = tid + it * NTHREADS;
      const int dg = c >> 6, tt = c & 63;
      const float* src = vp + (((size_t)b * SS + (t0 + tt)) * NKV + kh) * DD + dg * 8;
      #pragma unroll
      for (int j = 0; j < 8; ++j) vbuf[dg * 8 + j][tt] = src[j];
    }
    __syncthreads();

    if (t0 > qw + 15) continue;

    // ---- QK^T: sf[cc][j] = S[qw + lhi*4 + j][t0 + cc*16 + llo] ----
    float sf[4][4];
    #pragma unroll
    for (int cc = 0; cc < 4; ++cc) {
      const int r = cc * 16 + llo;
      #pragma unroll
      for (int j = 0; j < 4; ++j) {
        const int row = lhi * 4 + j;
        float acc = 0.f;
        #pragma unroll
        for (int s8 = 0; s8 < 16; ++s8) {
          short8 qv = __builtin_bit_cast(short8, qbuf_w[row * 16 + s8]);
          #pragma unroll
          for (int e = 0; e < 8; ++e)
            acc += bf2f(qv[e]) * kbuf[r][s8 * 8 + e];
        }
        sf[cc][j] = acc;
      }
    }

    // ---- causal mask ----
    if (t0 + KVBLK - 1 > qw) {
      #pragma unroll
      for (int cc = 0; cc < 4; ++cc)
        #pragma unroll
        for (int j = 0; j < 4; ++j) {
          const int tg = t0 + cc * 16 + llo;
          const int qg = qw + lhi * 4 + j;
          if (tg > qg) sf[cc][j] = -1e30f;
        }
    }

    // ---- online softmax ----
    #pragma unroll
    for (int j = 0; j < 4; ++j) {
      float mx = fmaxf(fmaxf(sf[0][j], sf[1][j]), fmaxf(sf[2][j], sf[3][j]));
      #pragma unroll
      for (int off = 1; off < 16; off <<= 1)
        mx = fmaxf(mx, __shfl_xor(mx, off));
      const float mnew = fmaxf(m_i[j], mx);
      const float corr = __expf(m_i[j] - mnew);
      m_i[j] = mnew;
      float s = 0.f;
      #pragma unroll
      for (int cc = 0; cc < 4; ++cc) {
        const float p = __expf(sf[cc][j] - mnew);
        sf[cc][j] = p;
        s += p;
      }
      #pragma unroll
      for (int off = 1; off < 16; off <<= 1)
        s += __shfl_xor(s, off);
      l_i[j] = l_i[j] * corr + s;
      #pragma unroll
      for (int f = 0; f < 8; ++f) oaccf[f][j] *= corr;
    }

    // ---- P -> per-wave LDS (fp32, unswizzled) ----
    #pragma unroll
    for (int cc = 0; cc < 4; ++cc)
      #pragma unroll
      for (int j = 0; j < 4; ++j)
        pbuf[wave][lhi * 4 + j][cc * 16 + llo] = sf[cc][j];

    asm volatile("s_waitcnt lgkmcnt(0)" ::: "memory");
    __builtin_amdgcn_sched_barrier(0);

    // ---- PV: oaccf[f][j] += sum_t P[row][t] * V[t][dd] ----
    #pragma unroll
    for (int f = 0; f < 8; ++f) {
      const int dd = f * 16 + llo;
      #pragma unroll
      for (int j = 0; j < 4; ++j) {
        const int row = lhi * 4 + j;
        float acc = 0.f;
        #pragma unroll
        for (int s8 = 0; s8 < 8; ++s8)
          #pragma unroll
          for (int e = 0; e < 8; ++e)
            acc += pbuf[wave][row][s8 * 8 + e] * vbuf[dd][s8 * 8 + e];
        oaccf[f][j] += acc;
      }
    }
  }

  // ---- epilogue ----
  #pragma unroll
  for (int j = 0; j < 4; ++j) {
    const float inv = 1.f / l_i[j];
    const int qg = qw + lhi * 4 + j;
    float* orow = op + (((size_t)b * SS + qg) * NH + h) * DD;
    #pragma unroll
    for (int f = 0; f < 8; ++f)
      orow[f * 16 + llo] = oaccf[f][j] * inv;
  }
}

extern "C" void kernel_launch(void* const* d_in, const int* in_sizes, int n_in,
                              void* d_out, int out_size, void* d_ws, size_t ws_size,
                              hipStream_t stream) {
  const float* q = (const float*)d_in[0];
  const float* k = (const float*)d_in[1];
  const float* v = (const float*)d_in[2];
  float* out = (float*)d_out;
  dim3 grid(BB * NH * NQT);
  dim3 block(NTHREADS);
  attn_skel<<<grid, block, 0, stream>>>(q, k, v, out);
}